// Round 2
// baseline (723.979 us; speedup 1.0000x reference)
//
#include <hip/hip_runtime.h>

#define B_ 16
#define H_ 12
#define N_ 784
#define NN_ (N_ * N_)      // 614656
#define NF4_ (N_ / 4)      // 196 float4 per row
#define BPB_ 128           // blocks per batch for softmax passes

typedef float f4 __attribute__((ext_vector_type(4)));

// ---- init: zero per-batch max bits and sums (ws is poisoned 0xAA) ----
__global__ void init_kernel(int* __restrict__ maxbits, float* __restrict__ sums) {
    int t = threadIdx.x;
    if (t < B_) { maxbits[t] = 0; sums[t] = 0.0f; }
}

// ---- pass 1: fused rowsum + head-weighted aggregate + per-batch max ----
// One wave per (b,i) row; head rows held in registers; nontemporal loads so
// the 472 MB one-shot read doesn't evict agg from L2/L3.
__global__ __launch_bounds__(256) void agg_kernel(
    const f4* __restrict__ m4, f4* __restrict__ agg4,
    int* __restrict__ maxbits) {
    const int lane = threadIdx.x & 63;
    const int wave = threadIdx.x >> 6;
    const int i    = blockIdx.x * 4 + wave;   // row in [0, N)
    const int b    = blockIdx.y;

    f4 acc[4];
#pragma unroll
    for (int k = 0; k < 4; ++k) acc[k] = (f4)0.f;

    const f4* rowbase = m4 + ((size_t)b * H_ * N_ + i) * NF4_;

#pragma unroll 2
    for (int h = 0; h < H_; ++h) {
        const f4* p = rowbase + (size_t)h * N_ * NF4_;
        f4 r[4];
        float s = 0.f;
#pragma unroll
        for (int k = 0; k < 4; ++k) {
            const int idx = k * 64 + lane;
            if (idx < NF4_) {
                r[k] = __builtin_nontemporal_load(p + idx);
                s += r[k].x + r[k].y + r[k].z + r[k].w;
            } else {
                r[k] = (f4)0.f;
            }
        }
#pragma unroll
        for (int off = 32; off > 0; off >>= 1) s += __shfl_xor(s, off, 64);
#pragma unroll
        for (int k = 0; k < 4; ++k) acc[k] += r[k] * s;
    }

    f4* outp = agg4 + ((size_t)b * N_ + i) * NF4_;
    float mx = 0.f;   // all values >= 0
#pragma unroll
    for (int k = 0; k < 4; ++k) {
        const int idx = k * 64 + lane;
        if (idx < NF4_) {
            outp[idx] = acc[k];
            mx = fmaxf(mx, fmaxf(fmaxf(acc[k].x, acc[k].y),
                                 fmaxf(acc[k].z, acc[k].w)));
        }
    }
#pragma unroll
    for (int off = 32; off > 0; off >>= 1)
        mx = fmaxf(mx, __shfl_xor(mx, off, 64));
    if (lane == 0) atomicMax(&maxbits[b], __float_as_int(mx));
}

// ---- pass 2: read-only per-batch sum of exp(x - max_b) ----
__global__ __launch_bounds__(256) void sumexp_kernel(
    const f4* __restrict__ agg4, const int* __restrict__ maxbits,
    float* __restrict__ sums) {
    const int b   = blockIdx.x >> 7;          // / BPB_
    const int blk = blockIdx.x & (BPB_ - 1);
    const float mx = __int_as_float(maxbits[b]);
    const f4* p = agg4 + (size_t)b * (NN_ / 4);
    float s = 0.f;
    for (int idx = blk * 256 + threadIdx.x; idx < NN_ / 4; idx += BPB_ * 256) {
        f4 v = p[idx];
        s += __expf(v.x - mx) + __expf(v.y - mx) +
             __expf(v.z - mx) + __expf(v.w - mx);
    }
#pragma unroll
    for (int off = 32; off > 0; off >>= 1) s += __shfl_xor(s, off, 64);
    __shared__ float red[4];
    if ((threadIdx.x & 63) == 0) red[threadIdx.x >> 6] = s;
    __syncthreads();
    if (threadIdx.x == 0)
        atomicAdd(&sums[b], red[0] + red[1] + red[2] + red[3]);
}

// ---- pass 3: out = exp(x - max_b) / sum_b (recompute exp; one R + one W) ----
__global__ __launch_bounds__(256) void finalize_kernel(
    f4* __restrict__ agg4, const int* __restrict__ maxbits,
    const float* __restrict__ sums) {
    const int b   = blockIdx.x >> 7;
    const int blk = blockIdx.x & (BPB_ - 1);
    const float mx  = __int_as_float(maxbits[b]);
    const float inv = 1.0f / sums[b];
    f4* p = agg4 + (size_t)b * (NN_ / 4);
    for (int idx = blk * 256 + threadIdx.x; idx < NN_ / 4; idx += BPB_ * 256) {
        f4 v = p[idx];
        v.x = __expf(v.x - mx) * inv;
        v.y = __expf(v.y - mx) * inv;
        v.z = __expf(v.z - mx) * inv;
        v.w = __expf(v.w - mx) * inv;
        p[idx] = v;
    }
}

extern "C" void kernel_launch(void* const* d_in, const int* in_sizes, int n_in,
                              void* d_out, int out_size, void* d_ws,
                              size_t ws_size, hipStream_t stream) {
    const f4* m4 = (const f4*)d_in[0];
    f4* out4 = (f4*)d_out;                 // doubles as agg scratch
    int*   maxbits = (int*)d_ws;
    float* sums    = (float*)((char*)d_ws + B_ * sizeof(int));

    hipLaunchKernelGGL(init_kernel, dim3(1), dim3(64), 0, stream,
                       maxbits, sums);
    hipLaunchKernelGGL(agg_kernel, dim3(N_ / 4, B_), dim3(256), 0, stream,
                       m4, out4, maxbits);
    hipLaunchKernelGGL(sumexp_kernel, dim3(B_ * BPB_), dim3(256), 0, stream,
                       out4, maxbits, (float*)sums);
    hipLaunchKernelGGL(finalize_kernel, dim3(B_ * BPB_), dim3(256), 0, stream,
                       out4, maxbits, (const float*)sums);
}